// Round 1
// baseline (255.968 us; speedup 1.0000x reference)
//
#include <hip/hip_runtime.h>
#include <hip/hip_bf16.h>
#include <math.h>

#define N_TOK 8192
#define HDIM  1024
#define NE    8
#define BM    256
#define BN    256
#define BK    64
#define NKT   (HDIM / BK)          // 16 K-steps
#define MT_MAX 32                  // 32*256 = 8192 rows capacity per expert (fully general)
#define NT_N  (HDIM / BN)          // 4 n-tiles
#define GEMM_GRID (NE * NT_N * MT_MAX)   // 1024 blocks, ~256 active when balanced
#define NCONV 8192                 // convert_w blocks
#define NGATE (N_TOK / 4)          // gate blocks (4 tokens each)

typedef __attribute__((ext_vector_type(8))) short bf16x8;
typedef __attribute__((ext_vector_type(4))) float f32x4;
typedef unsigned short u16;

__device__ __forceinline__ u16 f2bf(float f) {
    union { float f; unsigned u; } v; v.f = f;
    unsigned r = v.u + 0x7FFFu + ((v.u >> 16) & 1u);   // round-to-nearest-even
    return (u16)(r >> 16);
}

__device__ __forceinline__ void gld_lds16(const void* g, void* lds) {
    __builtin_amdgcn_global_load_lds(
        (const __attribute__((address_space(1))) unsigned int*)g,
        (__attribute__((address_space(3))) unsigned int*)lds,
        16, 0, 0);
}

// ---- prep: blocks [0,NGATE) gate+x->bf16 (long, start first); rest convert expert_w ----
__global__ __launch_bounds__(256)
void prep_kernel(const float* __restrict__ w, u16* __restrict__ wbf,
                 const float* __restrict__ x,
                 const float* __restrict__ gate_w,
                 const float* __restrict__ gate_b,
                 u16* __restrict__ xbf,
                 int* __restrict__ eids,       // [N_TOK] e0 | e1<<8
                 float2* __restrict__ gatesv)  // [N_TOK] (g0,g1)
{
    int bid = blockIdx.x;
    if (bid >= NGATE) {
        size_t i = (size_t)(bid - NGATE) * 256 + threadIdx.x;   // float4 index
        float4 v = ((const float4*)w)[i];
        ushort4 b;
        b.x = f2bf(v.x); b.y = f2bf(v.y); b.z = f2bf(v.z); b.w = f2bf(v.w);
        ((ushort4*)wbf)[i] = b;
        return;
    }
    int wave = threadIdx.x >> 6, lane = threadIdx.x & 63;
    int t = bid * 4 + wave;
    const float4* xt = (const float4*)(x + (size_t)t * HDIM);
    ushort4* xb = (ushort4*)(xbf + (size_t)t * HDIM);

    float acc[NE];
#pragma unroll
    for (int e = 0; e < NE; ++e) acc[e] = 0.f;

#pragma unroll
    for (int i = 0; i < 4; ++i) {
        int f = i * 64 + lane;
        float4 v = xt[f];
        ushort4 b;
        b.x = f2bf(v.x); b.y = f2bf(v.y); b.z = f2bf(v.z); b.w = f2bf(v.w);
        xb[f] = b;
#pragma unroll
        for (int e = 0; e < NE; ++e) {
            float4 wv = ((const float4*)(gate_w + e * HDIM))[f];
            acc[e] += v.x * wv.x + v.y * wv.y + v.z * wv.z + v.w * wv.w;
        }
    }
#pragma unroll
    for (int e = 0; e < NE; ++e)
        for (int off = 32; off > 0; off >>= 1)
            acc[e] += __shfl_down(acc[e], off);

    if (lane == 0) {
        float logit[NE];
        float mx = -1e30f;
#pragma unroll
        for (int e = 0; e < NE; ++e) {
            logit[e] = acc[e] + gate_b[e];
            mx = fmaxf(mx, logit[e]);
        }
        float p[NE], s = 0.f;
#pragma unroll
        for (int e = 0; e < NE; ++e) { p[e] = expf(logit[e] - mx); s += p[e]; }
        float inv = 1.f / s;
        int i0 = 0;
#pragma unroll
        for (int e = 1; e < NE; ++e) if (logit[e] > logit[i0]) i0 = e;
        int i1 = (i0 == 0) ? 1 : 0;
#pragma unroll
        for (int e = 0; e < NE; ++e) if (e != i0 && logit[e] > logit[i1]) i1 = e;

        eids[t]   = i0 | (i1 << 8);
        gatesv[t] = make_float2(p[i0] * inv, p[i1] * inv);
    }
}

// ---- compact: single block, hist+rank+scatter (16 sub-histograms) ----
__global__ __launch_bounds__(1024)
void compact_kernel(const int* __restrict__ eids,
                    const float2* __restrict__ gatesv,
                    int* __restrict__ tok_list, float* __restrict__ gate_list,
                    int* __restrict__ counts)
{
    __shared__ int lh[16][NE];
    __shared__ int lbase[16][NE];
    int tid = threadIdx.x;
    if (tid < 16 * NE) ((int*)lh)[tid] = 0;
    __syncthreads();
    int bucket = tid & 15;

    int e0v[8], e1v[8], r0v[8], r1v[8];
    float2 gv[8];
#pragma unroll
    for (int it = 0; it < 8; ++it) {
        int t = it * 1024 + tid;
        int ee = eids[t];
        e0v[it] = ee & 255; e1v[it] = (ee >> 8) & 255;
        gv[it] = gatesv[t];
        r0v[it] = atomicAdd(&lh[bucket][e0v[it]], 1);
        r1v[it] = atomicAdd(&lh[bucket][e1v[it]], 1);
    }
    __syncthreads();
    if (tid < NE) {
        int run = 0;
        for (int b = 0; b < 16; ++b) { lbase[b][tid] = run; run += lh[b][tid]; }
        counts[tid] = run;
    }
    __syncthreads();
#pragma unroll
    for (int it = 0; it < 8; ++it) {
        int t = it * 1024 + tid;
        int p0 = lbase[bucket][e0v[it]] + r0v[it];
        tok_list[e0v[it] * N_TOK + p0]  = t * 2;        // token*2 + slot
        gate_list[e0v[it] * N_TOK + p0] = gv[it].x;
        int p1 = lbase[bucket][e1v[it]] + r1v[it];
        tok_list[e1v[it] * N_TOK + p1]  = t * 2 + 1;
        gate_list[e1v[it] * N_TOK + p1] = gv[it].y;
    }
}

// ---- grouped per-expert GEMM, 256x256 tile, 8 waves, double-buffered 2-phase ----
// bid = idx*8 + e  =>  XCD (bid%8 empirical) == expert e: all ~32 active blocks of an
// expert run on ONE XCD; its 2MB weight slice + gathered A rows go L2-resident.
// LDS per matrix per buffer: 2048 slots of 16B. Slot s holds (row = s>>3,
// chunk = (s&7)^(row&7)) -- same chunk-XOR swizzle as the 128^2 version (0 conflicts).
// K-loop: minimum 2-phase pipeline -- issue STAGE(next buf) BEFORE compute(cur buf),
// one drain+barrier per K-step (__syncthreads emits vmcnt(0)+lgkmcnt(0)+s_barrier).
// Epilogue: global_atomic_add_f32 into pre-zeroed out (both slots), combine kernel gone.
__global__ __launch_bounds__(512)
void moe_gemm_kernel(const u16* __restrict__ xbf,
                     const u16* __restrict__ wbf,
                     const float* __restrict__ expert_b,
                     const int* __restrict__ counts,
                     const int* __restrict__ tok_list,
                     const float* __restrict__ gate_list,
                     float* __restrict__ out)
{
    int bid = blockIdx.x;
    int e   = bid & 7;
    int idx = bid >> 3;
    int n0  = (idx & 3) * BN;
    int m0  = (idx >> 2) * BM;
    int cnt = counts[e];
    if (m0 >= cnt) return;

    __shared__ __align__(16) u16 As[2][2048 * 8];   // 2 x 32 KB
    __shared__ __align__(16) u16 Bs[2][2048 * 8];   // 2 x 32 KB  (128 KB total)

    int tid = threadIdx.x;
    int w = tid >> 6, l = tid & 63;

    const u16* aP[4];
    const u16* bP[4];
#pragma unroll
    for (int j = 0; j < 4; ++j) {
        int s = j * 512 + tid;          // slot 0..2047
        int r = s >> 3;                 // row 0..255
        int cs = (s & 7) ^ (r & 7);     // pre-swizzled source chunk
        int tr = m0 + r; if (tr > cnt - 1) tr = cnt - 1;   // dup rows discarded in epilogue
        int lst = tok_list[e * N_TOK + tr];
        aP[j] = xbf + (size_t)(lst >> 1) * HDIM + cs * 8;
        bP[j] = wbf + (size_t)(e * HDIM + n0 + r) * HDIM + cs * 8;
    }

    int wm = (w >> 2) * 128, wn = (w & 3) * 64;   // 2 M-groups x 4 N-groups of waves
    int lrow = l & 15, quad = l >> 4;
    int cxbase = lrow & 7;

    f32x4 acc[8][4];
#pragma unroll
    for (int mi = 0; mi < 8; ++mi)
#pragma unroll
        for (int ni = 0; ni < 4; ++ni)
            acc[mi][ni] = (f32x4){0.f, 0.f, 0.f, 0.f};

    auto stage = [&](int b, int k0) {
#pragma unroll
        for (int j = 0; j < 4; ++j) {
            gld_lds16(aP[j] + k0, &As[b][(size_t)(j * 512 + w * 64) * 8]);
            gld_lds16(bP[j] + k0, &Bs[b][(size_t)(j * 512 + w * 64) * 8]);
        }
    };

    int buf = 0;
    stage(0, 0);
    __syncthreads();                    // drain prologue loads

    for (int kt = 0; kt < NKT; ++kt) {
        if (kt + 1 < NKT) stage(buf ^ 1, (kt + 1) * BK);   // prefetch next K-tile
#pragma unroll
        for (int kk = 0; kk < 2; ++kk) {
            int cx = (kk * 4 + quad) ^ cxbase;              // swizzled chunk for this lane
            bf16x8 bfr[4];
#pragma unroll
            for (int ni = 0; ni < 4; ++ni) {
                int rb = wn + ni * 16 + lrow;
                bfr[ni] = *(const bf16x8*)(&Bs[buf][(size_t)(rb * 8 + cx) * 8]);
            }
#pragma unroll
            for (int mi = 0; mi < 8; ++mi) {
                int ra = wm + mi * 16 + lrow;
                bf16x8 af = *(const bf16x8*)(&As[buf][(size_t)(ra * 8 + cx) * 8]);
#pragma unroll
                for (int ni = 0; ni < 4; ++ni)
                    acc[mi][ni] = __builtin_amdgcn_mfma_f32_16x16x32_bf16(
                        af, bfr[ni], acc[mi][ni], 0, 0, 0);
            }
        }
        __syncthreads();                // drains prefetch (vmcnt) + LDS reads (lgkm)
        buf ^= 1;
    }

    // epilogue: bias + gate, atomic-add both slots into pre-zeroed out
    float bias[4];
#pragma unroll
    for (int ni = 0; ni < 4; ++ni)
        bias[ni] = expert_b[e * HDIM + n0 + wn + ni * 16 + lrow];

#pragma unroll
    for (int mi = 0; mi < 8; ++mi) {
#pragma unroll
        for (int rr = 0; rr < 4; ++rr) {
            int listRow = m0 + wm + mi * 16 + quad * 4 + rr;
            if (listRow < cnt) {
                int   lst = tok_list[e * N_TOK + listRow];
                float g   = gate_list[e * N_TOK + listRow];
                float* dst = out + (size_t)(lst >> 1) * HDIM + n0 + wn;
#pragma unroll
                for (int ni = 0; ni < 4; ++ni)
                    atomicAdd(&dst[ni * 16 + lrow], (acc[mi][ni][rr] + bias[ni]) * g);
            }
        }
    }
}

extern "C" void kernel_launch(void* const* d_in, const int* in_sizes, int n_in,
                              void* d_out, int out_size, void* d_ws, size_t ws_size,
                              hipStream_t stream)
{
    const float* x        = (const float*)d_in[0];
    const float* gate_w   = (const float*)d_in[1];
    const float* gate_b   = (const float*)d_in[2];
    const float* expert_w = (const float*)d_in[3];
    const float* expert_b = (const float*)d_in[4];
    float* out = (float*)d_out;

    char* ws = (char*)d_ws;
    int*    eids      = (int*)(ws);                         // 32 KB
    float2* gatesv    = (float2*)(ws + (64 << 10));         // 64 KB
    int*    counts    = (int*)(ws + (132 << 10));           // 256 B
    int*    tok_list  = (int*)(ws + (136 << 10));           // 256 KB
    float*  gate_list = (float*)(ws + (136 << 10) + NE * N_TOK * 4); // 256 KB
    u16*    xbf       = (u16*)(ws + (1 << 20));             // 16 MB
    u16*    wbf       = xbf + (size_t)N_TOK * HDIM;         // 16 MB

    hipMemsetAsync(out, 0, (size_t)N_TOK * HDIM * sizeof(float), stream);

    prep_kernel<<<NCONV + NGATE, 256, 0, stream>>>(expert_w, wbf, x, gate_w, gate_b,
                                                   xbf, eids, gatesv);
    compact_kernel<<<1, 1024, 0, stream>>>(eids, gatesv, tok_list, gate_list, counts);

    moe_gemm_kernel<<<GEMM_GRID, 512, 0, stream>>>(xbf, wbf, expert_b,
                                                   counts, tok_list, gate_list, out);
}

// Round 2
// 217.553 us; speedup vs baseline: 1.1766x; 1.1766x over previous
//
#include <hip/hip_runtime.h>
#include <hip/hip_bf16.h>
#include <math.h>

#define N_TOK 8192
#define HDIM  1024
#define NE    8
#define BM    256
#define BN    256
#define BK    64
#define NKT   (HDIM / BK)          // 16 K-steps
#define MT_MAX 32                  // 32*256 = 8192 rows capacity per expert (fully general)
#define NT_N  (HDIM / BN)          // 4 n-tiles
#define GEMM_GRID (NE * NT_N * MT_MAX)   // 1024 blocks, ~256 active when balanced
#define NCONV 8192                 // convert_w blocks
#define NGATE (N_TOK / 4)          // gate blocks (4 tokens each)

typedef __attribute__((ext_vector_type(8))) short bf16x8;
typedef __attribute__((ext_vector_type(4))) float f32x4;
typedef unsigned short u16;

__device__ __forceinline__ u16 f2bf(float f) {
    union { float f; unsigned u; } v; v.f = f;
    unsigned r = v.u + 0x7FFFu + ((v.u >> 16) & 1u);   // round-to-nearest-even
    return (u16)(r >> 16);
}

__device__ __forceinline__ void gld_lds16(const void* g, void* lds) {
    __builtin_amdgcn_global_load_lds(
        (const __attribute__((address_space(1))) unsigned int*)g,
        (__attribute__((address_space(3))) unsigned int*)lds,
        16, 0, 0);
}

// ---- prep: blocks [0,NGATE) gate+x->bf16 (long, start first); rest convert expert_w ----
__global__ __launch_bounds__(256)
void prep_kernel(const float* __restrict__ w, u16* __restrict__ wbf,
                 const float* __restrict__ x,
                 const float* __restrict__ gate_w,
                 const float* __restrict__ gate_b,
                 u16* __restrict__ xbf,
                 int* __restrict__ eids,       // [N_TOK] e0 | e1<<8
                 float2* __restrict__ gatesv)  // [N_TOK] (g0,g1)
{
    int bid = blockIdx.x;
    if (bid >= NGATE) {
        size_t i = (size_t)(bid - NGATE) * 256 + threadIdx.x;   // float4 index
        float4 v = ((const float4*)w)[i];
        ushort4 b;
        b.x = f2bf(v.x); b.y = f2bf(v.y); b.z = f2bf(v.z); b.w = f2bf(v.w);
        ((ushort4*)wbf)[i] = b;
        return;
    }
    int wave = threadIdx.x >> 6, lane = threadIdx.x & 63;
    int t = bid * 4 + wave;
    const float4* xt = (const float4*)(x + (size_t)t * HDIM);
    ushort4* xb = (ushort4*)(xbf + (size_t)t * HDIM);

    float acc[NE];
#pragma unroll
    for (int e = 0; e < NE; ++e) acc[e] = 0.f;

#pragma unroll
    for (int i = 0; i < 4; ++i) {
        int f = i * 64 + lane;
        float4 v = xt[f];
        ushort4 b;
        b.x = f2bf(v.x); b.y = f2bf(v.y); b.z = f2bf(v.z); b.w = f2bf(v.w);
        xb[f] = b;
#pragma unroll
        for (int e = 0; e < NE; ++e) {
            float4 wv = ((const float4*)(gate_w + e * HDIM))[f];
            acc[e] += v.x * wv.x + v.y * wv.y + v.z * wv.z + v.w * wv.w;
        }
    }
#pragma unroll
    for (int e = 0; e < NE; ++e)
        for (int off = 32; off > 0; off >>= 1)
            acc[e] += __shfl_down(acc[e], off);

    if (lane == 0) {
        float logit[NE];
        float mx = -1e30f;
#pragma unroll
        for (int e = 0; e < NE; ++e) {
            logit[e] = acc[e] + gate_b[e];
            mx = fmaxf(mx, logit[e]);
        }
        float p[NE], s = 0.f;
#pragma unroll
        for (int e = 0; e < NE; ++e) { p[e] = expf(logit[e] - mx); s += p[e]; }
        float inv = 1.f / s;
        int i0 = 0;
#pragma unroll
        for (int e = 1; e < NE; ++e) if (logit[e] > logit[i0]) i0 = e;
        int i1 = (i0 == 0) ? 1 : 0;
#pragma unroll
        for (int e = 0; e < NE; ++e) if (e != i0 && logit[e] > logit[i1]) i1 = e;

        eids[t]   = i0 | (i1 << 8);
        gatesv[t] = make_float2(p[i0] * inv, p[i1] * inv);
    }
}

// ---- compact: single block, hist+rank+scatter (16 sub-histograms) ----
__global__ __launch_bounds__(1024)
void compact_kernel(const int* __restrict__ eids,
                    const float2* __restrict__ gatesv,
                    int* __restrict__ tok_list, float* __restrict__ gate_list,
                    int* __restrict__ counts)
{
    __shared__ int lh[16][NE];
    __shared__ int lbase[16][NE];
    int tid = threadIdx.x;
    if (tid < 16 * NE) ((int*)lh)[tid] = 0;
    __syncthreads();
    int bucket = tid & 15;

    int e0v[8], e1v[8], r0v[8], r1v[8];
    float2 gv[8];
#pragma unroll
    for (int it = 0; it < 8; ++it) {
        int t = it * 1024 + tid;
        int ee = eids[t];
        e0v[it] = ee & 255; e1v[it] = (ee >> 8) & 255;
        gv[it] = gatesv[t];
        r0v[it] = atomicAdd(&lh[bucket][e0v[it]], 1);
        r1v[it] = atomicAdd(&lh[bucket][e1v[it]], 1);
    }
    __syncthreads();
    if (tid < NE) {
        int run = 0;
        for (int b = 0; b < 16; ++b) { lbase[b][tid] = run; run += lh[b][tid]; }
        counts[tid] = run;
    }
    __syncthreads();
#pragma unroll
    for (int it = 0; it < 8; ++it) {
        int t = it * 1024 + tid;
        int p0 = lbase[bucket][e0v[it]] + r0v[it];
        tok_list[e0v[it] * N_TOK + p0]  = t * 2;        // token*2 + slot
        gate_list[e0v[it] * N_TOK + p0] = gv[it].x;
        int p1 = lbase[bucket][e1v[it]] + r1v[it];
        tok_list[e1v[it] * N_TOK + p1]  = t * 2 + 1;
        gate_list[e1v[it] * N_TOK + p1] = gv[it].y;
    }
}

// ---- grouped per-expert GEMM, 256x256 tile, 8 waves, counted-vmcnt double-buffer ----
// bid = idx*8 + e  =>  XCD (bid%8 empirical) == expert e: all ~32 active blocks of an
// expert run on ONE XCD; its 2MB weight slice + gathered A rows go L2-resident
// (round-1 measured FETCH 81MB -> 26.6MB with this mapping; keep it).
// LDS per matrix per buffer: 2048 slots of 16B. Slot s holds (row = s>>3,
// chunk = (s&7)^(row&7)) -- chunk-XOR swizzle, pre-swizzled global source +
// swizzled ds_read (rule-21 both-sides; 0 bank conflicts measured).
// K-loop (T4, counted vmcnt -- NO vmcnt(0) drain in main loop):
//   prologue: stage(buf0,k0); stage(buf1,k1)      -> 16 loads/thread in flight
//   per kt:   vmcnt(8) [vmcnt(0) on last]         -> oldest batch (this kt) landed
//             s_barrier                            -> all waves' portions landed
//             ds_read + 64 MFMA on buf[kt&1]
//             lgkmcnt(0); s_barrier                -> all reads of buf done
//             stage(buf, kt+2)                     -> refill freed buffer
// "memory" clobbers on the waitcnt asms keep epilogue vmem ops out of the
// counted window. Epilogue: plain stores to (token,slot) partial rows.
__global__ __launch_bounds__(512)
void moe_gemm_kernel(const u16* __restrict__ xbf,
                     const u16* __restrict__ wbf,
                     const float* __restrict__ expert_b,
                     const int* __restrict__ counts,
                     const int* __restrict__ tok_list,
                     const float* __restrict__ gate_list,
                     float* __restrict__ out,      // slot0 partials
                     float* __restrict__ part1)    // slot1 partials
{
    int bid = blockIdx.x;
    int e   = bid & 7;
    int idx = bid >> 3;
    int n0  = (idx & 3) * BN;
    int m0  = (idx >> 2) * BM;
    int cnt = counts[e];
    if (m0 >= cnt) return;

    __shared__ __align__(16) u16 As[2][2048 * 8];   // 2 x 32 KB
    __shared__ __align__(16) u16 Bs[2][2048 * 8];   // 2 x 32 KB  (128 KB total)

    int tid = threadIdx.x;
    int w = tid >> 6, l = tid & 63;

    const u16* aP[4];
    const u16* bP[4];
#pragma unroll
    for (int j = 0; j < 4; ++j) {
        int s = j * 512 + tid;          // slot 0..2047
        int r = s >> 3;                 // row 0..255
        int cs = (s & 7) ^ (r & 7);     // pre-swizzled source chunk
        int tr = m0 + r; if (tr > cnt - 1) tr = cnt - 1;   // dup rows discarded in epilogue
        int lst = tok_list[e * N_TOK + tr];
        aP[j] = xbf + (size_t)(lst >> 1) * HDIM + cs * 8;
        bP[j] = wbf + (size_t)(e * HDIM + n0 + r) * HDIM + cs * 8;
    }

    int wm = (w >> 2) * 128, wn = (w & 3) * 64;   // 2 M-groups x 4 N-groups of waves
    int lrow = l & 15, quad = l >> 4;
    int cxbase = lrow & 7;

    f32x4 acc[8][4];
#pragma unroll
    for (int mi = 0; mi < 8; ++mi)
#pragma unroll
        for (int ni = 0; ni < 4; ++ni)
            acc[mi][ni] = (f32x4){0.f, 0.f, 0.f, 0.f};

    auto stage = [&](int b, int k0) {
#pragma unroll
        for (int j = 0; j < 4; ++j) {
            gld_lds16(aP[j] + k0, &As[b][(size_t)(j * 512 + w * 64) * 8]);
            gld_lds16(bP[j] + k0, &Bs[b][(size_t)(j * 512 + w * 64) * 8]);
        }
    };

    // prologue: both buffers in flight (8 loads/thread each)
    stage(0, 0);
    stage(1, BK);

    int buf = 0;
    for (int kt = 0; kt < NKT; ++kt) {
        // oldest 8 loads (== buffer for this kt) retired; in-order vmcnt
        if (kt == NKT - 1) asm volatile("s_waitcnt vmcnt(0)" ::: "memory");
        else               asm volatile("s_waitcnt vmcnt(8)" ::: "memory");
        __builtin_amdgcn_s_barrier();

        const u16* Ab = As[buf];
        const u16* Bb = Bs[buf];
#pragma unroll
        for (int kk = 0; kk < 2; ++kk) {
            int cx = (kk * 4 + quad) ^ cxbase;              // swizzled chunk for this lane
            bf16x8 bfr[4];
#pragma unroll
            for (int ni = 0; ni < 4; ++ni) {
                int rb = wn + ni * 16 + lrow;
                bfr[ni] = *(const bf16x8*)(Bb + (size_t)(rb * 8 + cx) * 8);
            }
#pragma unroll
            for (int mi = 0; mi < 8; ++mi) {
                int ra = wm + mi * 16 + lrow;
                bf16x8 af = *(const bf16x8*)(Ab + (size_t)(ra * 8 + cx) * 8);
#pragma unroll
                for (int ni = 0; ni < 4; ++ni)
                    acc[mi][ni] = __builtin_amdgcn_mfma_f32_16x16x32_bf16(
                        af, bfr[ni], acc[mi][ni], 0, 0, 0);
            }
        }

        asm volatile("s_waitcnt lgkmcnt(0)" ::: "memory");  // my ds_reads done
        __builtin_amdgcn_s_barrier();                       // everyone's reads done
        if (kt + 2 < NKT) stage(buf, (kt + 2) * BK);        // refill freed buffer
        buf ^= 1;
    }

    // epilogue: bias + gate, plain stores to (token,slot) partial rows
    float bias[4];
#pragma unroll
    for (int ni = 0; ni < 4; ++ni)
        bias[ni] = expert_b[e * HDIM + n0 + wn + ni * 16 + lrow];

#pragma unroll
    for (int mi = 0; mi < 8; ++mi) {
#pragma unroll
        for (int rr = 0; rr < 4; ++rr) {
            int listRow = m0 + wm + mi * 16 + quad * 4 + rr;
            if (listRow < cnt) {
                int   lst = tok_list[e * N_TOK + listRow];
                float g   = gate_list[e * N_TOK + listRow];
                float* dst = ((lst & 1) ? part1 : out) + (size_t)(lst >> 1) * HDIM + n0 + wn;
#pragma unroll
                for (int ni = 0; ni < 4; ++ni)
                    dst[ni * 16 + lrow] = (acc[mi][ni][rr] + bias[ni]) * g;
            }
        }
    }
}

// ---- combine: out += part1 ----
__global__ __launch_bounds__(256)
void combine_kernel(float* __restrict__ out, const float* __restrict__ part1) {
    size_t i = (size_t)blockIdx.x * 256 + threadIdx.x;
    float4 a = ((const float4*)out)[i];
    float4 b = ((const float4*)part1)[i];
    a.x += b.x; a.y += b.y; a.z += b.z; a.w += b.w;
    ((float4*)out)[i] = a;
}

extern "C" void kernel_launch(void* const* d_in, const int* in_sizes, int n_in,
                              void* d_out, int out_size, void* d_ws, size_t ws_size,
                              hipStream_t stream)
{
    const float* x        = (const float*)d_in[0];
    const float* gate_w   = (const float*)d_in[1];
    const float* gate_b   = (const float*)d_in[2];
    const float* expert_w = (const float*)d_in[3];
    const float* expert_b = (const float*)d_in[4];
    float* out = (float*)d_out;

    char* ws = (char*)d_ws;
    int*    eids      = (int*)(ws);                         // 32 KB
    float2* gatesv    = (float2*)(ws + (64 << 10));         // 64 KB
    int*    counts    = (int*)(ws + (132 << 10));           // 256 B
    int*    tok_list  = (int*)(ws + (136 << 10));           // 256 KB
    float*  gate_list = (float*)(ws + (136 << 10) + NE * N_TOK * 4); // 256 KB
    u16*    xbf       = (u16*)(ws + (1 << 20));             // 16 MB
    u16*    wbf       = xbf + (size_t)N_TOK * HDIM;         // 16 MB
    float*  part1     = (float*)(ws + (33u << 20));         // 32 MB

    prep_kernel<<<NCONV + NGATE, 256, 0, stream>>>(expert_w, wbf, x, gate_w, gate_b,
                                                   xbf, eids, gatesv);
    compact_kernel<<<1, 1024, 0, stream>>>(eids, gatesv, tok_list, gate_list, counts);

    moe_gemm_kernel<<<GEMM_GRID, 512, 0, stream>>>(xbf, wbf, expert_b,
                                                   counts, tok_list, gate_list, out, part1);

    combine_kernel<<<N_TOK * HDIM / 4 / 256, 256, 0, stream>>>(out, part1);
}

// Round 3
// 208.929 us; speedup vs baseline: 1.2251x; 1.0413x over previous
//
#include <hip/hip_runtime.h>
#include <hip/hip_bf16.h>
#include <math.h>

#define N_TOK 8192
#define HDIM  1024
#define NE    8
#define TILE  128
#define BK    64
#define NKT   (HDIM / BK)          // 16 K-steps
#define MT_MAX 64                  // 64*128 = 8192 rows capacity per expert (fully general)
#define NT_N  (HDIM / TILE)        // 8 n-tiles
#define GEMM_GRID (NE * NT_N * MT_MAX)   // 4096 blocks, ~1090 active when balanced
#define NCONV 8192                 // convert_w blocks
#define NGATE (N_TOK / 4)          // gate blocks (4 tokens each)

typedef __attribute__((ext_vector_type(8))) short bf16x8;
typedef __attribute__((ext_vector_type(4))) float f32x4;
typedef unsigned short u16;

__device__ __forceinline__ u16 f2bf(float f) {
    union { float f; unsigned u; } v; v.f = f;
    unsigned r = v.u + 0x7FFFu + ((v.u >> 16) & 1u);   // round-to-nearest-even
    return (u16)(r >> 16);
}

__device__ __forceinline__ void gld_lds16(const void* g, void* lds) {
    __builtin_amdgcn_global_load_lds(
        (const __attribute__((address_space(1))) unsigned int*)g,
        (__attribute__((address_space(3))) unsigned int*)lds,
        16, 0, 0);
}

// ---- prep: blocks [0,NGATE) gate+x->bf16 (long, start first); rest convert expert_w ----
__global__ __launch_bounds__(256)
void prep_kernel(const float* __restrict__ w, u16* __restrict__ wbf,
                 const float* __restrict__ x,
                 const float* __restrict__ gate_w,
                 const float* __restrict__ gate_b,
                 u16* __restrict__ xbf,
                 int* __restrict__ eids,       // [N_TOK] e0 | e1<<8
                 float2* __restrict__ gatesv)  // [N_TOK] (g0,g1)
{
    int bid = blockIdx.x;
    if (bid >= NGATE) {
        size_t i = (size_t)(bid - NGATE) * 256 + threadIdx.x;   // float4 index
        float4 v = ((const float4*)w)[i];
        ushort4 b;
        b.x = f2bf(v.x); b.y = f2bf(v.y); b.z = f2bf(v.z); b.w = f2bf(v.w);
        ((ushort4*)wbf)[i] = b;
        return;
    }
    int wave = threadIdx.x >> 6, lane = threadIdx.x & 63;
    int t = bid * 4 + wave;
    const float4* xt = (const float4*)(x + (size_t)t * HDIM);
    ushort4* xb = (ushort4*)(xbf + (size_t)t * HDIM);

    float acc[NE];
#pragma unroll
    for (int e = 0; e < NE; ++e) acc[e] = 0.f;

#pragma unroll
    for (int i = 0; i < 4; ++i) {
        int f = i * 64 + lane;
        float4 v = xt[f];
        ushort4 b;
        b.x = f2bf(v.x); b.y = f2bf(v.y); b.z = f2bf(v.z); b.w = f2bf(v.w);
        xb[f] = b;
#pragma unroll
        for (int e = 0; e < NE; ++e) {
            float4 wv = ((const float4*)(gate_w + e * HDIM))[f];
            acc[e] += v.x * wv.x + v.y * wv.y + v.z * wv.z + v.w * wv.w;
        }
    }
#pragma unroll
    for (int e = 0; e < NE; ++e)
        for (int off = 32; off > 0; off >>= 1)
            acc[e] += __shfl_down(acc[e], off);

    if (lane == 0) {
        float logit[NE];
        float mx = -1e30f;
#pragma unroll
        for (int e = 0; e < NE; ++e) {
            logit[e] = acc[e] + gate_b[e];
            mx = fmaxf(mx, logit[e]);
        }
        float p[NE], s = 0.f;
#pragma unroll
        for (int e = 0; e < NE; ++e) { p[e] = expf(logit[e] - mx); s += p[e]; }
        float inv = 1.f / s;
        int i0 = 0;
#pragma unroll
        for (int e = 1; e < NE; ++e) if (logit[e] > logit[i0]) i0 = e;
        int i1 = (i0 == 0) ? 1 : 0;
#pragma unroll
        for (int e = 0; e < NE; ++e) if (e != i0 && logit[e] > logit[i1]) i1 = e;

        eids[t]   = i0 | (i1 << 8);
        gatesv[t] = make_float2(p[i0] * inv, p[i1] * inv);
    }
}

// ---- compact: single block, hist+rank+scatter (16 sub-histograms) ----
__global__ __launch_bounds__(1024)
void compact_kernel(const int* __restrict__ eids,
                    const float2* __restrict__ gatesv,
                    int* __restrict__ tok_list, float* __restrict__ gate_list,
                    int* __restrict__ counts)
{
    __shared__ int lh[16][NE];
    __shared__ int lbase[16][NE];
    int tid = threadIdx.x;
    if (tid < 16 * NE) ((int*)lh)[tid] = 0;
    __syncthreads();
    int bucket = tid & 15;

    int e0v[8], e1v[8], r0v[8], r1v[8];
    float2 gv[8];
#pragma unroll
    for (int it = 0; it < 8; ++it) {
        int t = it * 1024 + tid;
        int ee = eids[t];
        e0v[it] = ee & 255; e1v[it] = (ee >> 8) & 255;
        gv[it] = gatesv[t];
        r0v[it] = atomicAdd(&lh[bucket][e0v[it]], 1);
        r1v[it] = atomicAdd(&lh[bucket][e1v[it]], 1);
    }
    __syncthreads();
    if (tid < NE) {
        int run = 0;
        for (int b = 0; b < 16; ++b) { lbase[b][tid] = run; run += lh[b][tid]; }
        counts[tid] = run;
    }
    __syncthreads();
#pragma unroll
    for (int it = 0; it < 8; ++it) {
        int t = it * 1024 + tid;
        int p0 = lbase[bucket][e0v[it]] + r0v[it];
        tok_list[e0v[it] * N_TOK + p0]  = t * 2;        // token*2 + slot
        gate_list[e0v[it] * N_TOK + p0] = gv[it].x;
        int p1 = lbase[bucket][e1v[it]] + r1v[it];
        tok_list[e1v[it] * N_TOK + p1]  = t * 2 + 1;
        gate_list[e1v[it] * N_TOK + p1] = gv[it].y;
    }
}

// ---- grouped per-expert GEMM, 128x128 tile, 4 waves, counted-vmcnt double-buffer ----
// Mapping: bid = (m*8 + n)*8 + e  =>  XCD (bid%8) == expert e. Per XCD: its expert's
// 8 n-slices of B (2 MB) go L2-resident; an m-tile's gathered A rows are reused by its
// 8 co-XCD n-blocks. ~136 active blocks/XCD over 64 resident slots (2 blocks/CU at
// 64 KB LDS) -> integer-tile tail ~1.1x (round-2's 256d tiles at 1 block/CU gave ~2x).
// LDS per matrix per buffer: 1024 slots of 16B. Slot s holds (row = s>>3,
// chunk = (s&7)^(row&7)) -- chunk-XOR swizzle, pre-swizzled global source +
// swizzled ds_read (rule-21 both-sides; 0 bank conflicts measured rounds 0-2).
// K-loop (T4, counted vmcnt -- NO vmcnt(0) drain in main loop):
//   prologue: stage(buf0,k0); stage(buf1,k1)      -> 16 loads/thread in flight
//   per kt:   vmcnt(8) [vmcnt(0) on last]         -> this kt's batch landed
//             s_barrier -> compute buf[kt&1] (16 ds_read_b128 + 32 MFMA / wave)
//             lgkmcnt(0); s_barrier -> stage(buf, kt+2) into freed buffer
// Epilogue: plain stores to (token,slot) partial rows; combine adds part1.
__global__ __launch_bounds__(256, 2)
void moe_gemm_kernel(const u16* __restrict__ xbf,
                     const u16* __restrict__ wbf,
                     const float* __restrict__ expert_b,
                     const int* __restrict__ counts,
                     const int* __restrict__ tok_list,
                     const float* __restrict__ gate_list,
                     float* __restrict__ out,      // slot0 partials
                     float* __restrict__ part1)    // slot1 partials
{
    int bid = blockIdx.x;
    int e   = bid & 7;                 // XCD pin
    int n0  = ((bid >> 3) & 7) * TILE;
    int m0  = (bid >> 6) * TILE;
    int cnt = counts[e];
    if (m0 >= cnt) return;

    __shared__ __align__(16) u16 As[2][1024 * 8];   // 2 x 16 KB
    __shared__ __align__(16) u16 Bs[2][1024 * 8];   // 2 x 16 KB  (64 KB total)

    int tid = threadIdx.x;
    int w = tid >> 6, l = tid & 63;

    const u16* aP[4];
    const u16* bP[4];
#pragma unroll
    for (int j = 0; j < 4; ++j) {
        int s = j * 256 + tid;          // slot 0..1023
        int r = s >> 3;                 // row 0..127
        int cs = (s & 7) ^ (r & 7);     // pre-swizzled source chunk
        int tr = m0 + r; if (tr > cnt - 1) tr = cnt - 1;   // dup rows discarded in epilogue
        int lst = tok_list[e * N_TOK + tr];
        aP[j] = xbf + (size_t)(lst >> 1) * HDIM + cs * 8;
        bP[j] = wbf + (size_t)(e * HDIM + n0 + r) * HDIM + cs * 8;
    }

    int wm = (w >> 1) * 64, wn = (w & 1) * 64;   // 2M x 2N wave grid
    int lrow = l & 15, quad = l >> 4;
    int cxbase = lrow & 7;

    f32x4 acc[4][4];
#pragma unroll
    for (int mi = 0; mi < 4; ++mi)
#pragma unroll
        for (int ni = 0; ni < 4; ++ni)
            acc[mi][ni] = (f32x4){0.f, 0.f, 0.f, 0.f};

    auto stage = [&](int b, int k0) {
#pragma unroll
        for (int j = 0; j < 4; ++j) {
            gld_lds16(aP[j] + k0, &As[b][(size_t)(j * 256 + w * 64) * 8]);
            gld_lds16(bP[j] + k0, &Bs[b][(size_t)(j * 256 + w * 64) * 8]);
        }
    };

    // prologue: both buffers in flight (8 loads/thread each)
    stage(0, 0);
    stage(1, BK);

    int buf = 0;
    for (int kt = 0; kt < NKT; ++kt) {
        // this kt's batch (oldest 8 loads) retired; newer 8 stay in flight
        if (kt == NKT - 1) asm volatile("s_waitcnt vmcnt(0)" ::: "memory");
        else               asm volatile("s_waitcnt vmcnt(8)" ::: "memory");
        __builtin_amdgcn_s_barrier();

        const u16* Ab = As[buf];
        const u16* Bb = Bs[buf];
#pragma unroll
        for (int kk = 0; kk < 2; ++kk) {
            int cx = (kk * 4 + quad) ^ cxbase;              // swizzled chunk for this lane
            bf16x8 af[4], bfr[4];
#pragma unroll
            for (int i = 0; i < 4; ++i) {
                int ra = wm + i * 16 + lrow;
                int rb = wn + i * 16 + lrow;
                af[i]  = *(const bf16x8*)(Ab + (size_t)(ra * 8 + cx) * 8);
                bfr[i] = *(const bf16x8*)(Bb + (size_t)(rb * 8 + cx) * 8);
            }
#pragma unroll
            for (int mi = 0; mi < 4; ++mi)
#pragma unroll
                for (int ni = 0; ni < 4; ++ni)
                    acc[mi][ni] = __builtin_amdgcn_mfma_f32_16x16x32_bf16(
                        af[mi], bfr[ni], acc[mi][ni], 0, 0, 0);
        }

        asm volatile("s_waitcnt lgkmcnt(0)" ::: "memory");  // my ds_reads done
        __builtin_amdgcn_s_barrier();                       // everyone's reads done
        if (kt + 2 < NKT) stage(buf, (kt + 2) * BK);        // refill freed buffer
        buf ^= 1;
    }

    // epilogue: bias + gate, plain stores to (token,slot) partial rows
#pragma unroll
    for (int mi = 0; mi < 4; ++mi) {
#pragma unroll
        for (int rr = 0; rr < 4; ++rr) {
            int listRow = m0 + wm + mi * 16 + quad * 4 + rr;
            if (listRow < cnt) {
                int   lst = tok_list[e * N_TOK + listRow];
                float g   = gate_list[e * N_TOK + listRow];
                float* dst = ((lst & 1) ? part1 : out) + (size_t)(lst >> 1) * HDIM;
#pragma unroll
                for (int ni = 0; ni < 4; ++ni) {
                    int col = n0 + wn + ni * 16 + lrow;
                    dst[col] = (acc[mi][ni][rr] + expert_b[e * HDIM + col]) * g;
                }
            }
        }
    }
}

// ---- combine: out += part1 ----
__global__ __launch_bounds__(256)
void combine_kernel(float* __restrict__ out, const float* __restrict__ part1) {
    size_t i = (size_t)blockIdx.x * 256 + threadIdx.x;
    float4 a = ((const float4*)out)[i];
    float4 b = ((const float4*)part1)[i];
    a.x += b.x; a.y += b.y; a.z += b.z; a.w += b.w;
    ((float4*)out)[i] = a;
}

extern "C" void kernel_launch(void* const* d_in, const int* in_sizes, int n_in,
                              void* d_out, int out_size, void* d_ws, size_t ws_size,
                              hipStream_t stream)
{
    const float* x        = (const float*)d_in[0];
    const float* gate_w   = (const float*)d_in[1];
    const float* gate_b   = (const float*)d_in[2];
    const float* expert_w = (const float*)d_in[3];
    const float* expert_b = (const float*)d_in[4];
    float* out = (float*)d_out;

    char* ws = (char*)d_ws;
    int*    eids      = (int*)(ws);                         // 32 KB
    float2* gatesv    = (float2*)(ws + (64 << 10));         // 64 KB
    int*    counts    = (int*)(ws + (132 << 10));           // 256 B
    int*    tok_list  = (int*)(ws + (136 << 10));           // 256 KB
    float*  gate_list = (float*)(ws + (136 << 10) + NE * N_TOK * 4); // 256 KB
    u16*    xbf       = (u16*)(ws + (1 << 20));             // 16 MB
    u16*    wbf       = xbf + (size_t)N_TOK * HDIM;         // 16 MB
    float*  part1     = (float*)(ws + (33u << 20));         // 32 MB

    prep_kernel<<<NCONV + NGATE, 256, 0, stream>>>(expert_w, wbf, x, gate_w, gate_b,
                                                   xbf, eids, gatesv);
    compact_kernel<<<1, 1024, 0, stream>>>(eids, gatesv, tok_list, gate_list, counts);

    moe_gemm_kernel<<<GEMM_GRID, 256, 0, stream>>>(xbf, wbf, expert_b,
                                                   counts, tok_list, gate_list, out, part1);

    combine_kernel<<<N_TOK * HDIM / 4 / 256, 256, 0, stream>>>(out, part1);
}